// Round 12
// baseline (112.300 us; speedup 1.0000x reference)
//
#include <hip/hip_runtime.h>
#include <math.h>

#define KW 7
#define PADW 12
#define BATCH 8
#define CIN 128
#define COUT 256
#define LEN 4096
#define L2V 4108
#define KCONV 896
#define PTILE 128

typedef unsigned short u16;
typedef short v8s __attribute__((ext_vector_type(8)));
typedef float v4f __attribute__((ext_vector_type(4)));

// 2-bit chunk swizzle key from row bits 0..2 (keeps ds_read_b128 <=2-way)
#define KEY3(r) ((((r) & 3) ^ (((r) >> 2) & 1)))

__device__ __forceinline__ u16 f2bf(float f) {
  unsigned int x = __float_as_uint(f);
  x += 0x7fffu + ((x >> 16) & 1u);
  return (u16)(x >> 16);
}
__device__ __forceinline__ float bf2f(u16 u) {
  return __uint_as_float(((unsigned int)u) << 16);
}

__device__ __forceinline__ void gll16(const void* g, void* l) {
  __builtin_amdgcn_global_load_lds(
      (const __attribute__((address_space(1))) void*)g,
      (__attribute__((address_space(3))) void*)l, 16, 0, 0);
}

__device__ __forceinline__ void wait_vm(int n) {
  switch (n) {
    case 0: asm volatile("s_waitcnt vmcnt(0)" ::: "memory"); break;
    case 2: asm volatile("s_waitcnt vmcnt(2)" ::: "memory"); break;
    case 3: asm volatile("s_waitcnt vmcnt(3)" ::: "memory"); break;
  }
}
#define LGKM0()  asm volatile("s_waitcnt lgkmcnt(0)" ::: "memory")
#define BARRIER() { __builtin_amdgcn_s_barrier(); asm volatile("" ::: "memory"); }

#define MFMA16(ACC, AA, BB)                                                    \
  { _Pragma("unroll") for (int fi_ = 0; fi_ < 4; ++fi_)                        \
    _Pragma("unroll") for (int fj_ = 0; fj_ < 4; ++fj_)                        \
      ACC[fi_][fj_] = __builtin_amdgcn_mfma_f32_16x16x32_bf16(                 \
          AA[fi_], BB[fj_], ACC[fi_][fj_], 0, 0, 0); }

// ---------------------------------------------------------------------------
// prep 1: weight norm -> wt[c][t][ci] bf16  (k = t*128+ci contiguous per c)
// ---------------------------------------------------------------------------
__global__ __launch_bounds__(256) void prep_wn(
    const float* __restrict__ v, const float* __restrict__ g,
    u16* __restrict__ wt)
{
  const int c = blockIdx.x;
  const float* vo = v + (size_t)c * (CIN * KW);
  float s = 0.f;
  for (int i = threadIdx.x; i < CIN * KW; i += 256) { float t = vo[i]; s += t * t; }
#pragma unroll
  for (int off = 1; off < 64; off <<= 1) s += __shfl_xor(s, off);
  __shared__ float red[4];
  if ((threadIdx.x & 63) == 0) red[threadIdx.x >> 6] = s;
  __syncthreads();
  const float tot = red[0] + red[1] + red[2] + red[3];
  const float scale = g[c] / sqrtf(tot);
  for (int i = threadIdx.x; i < CIN * KW; i += 256) {
    const int ci = i / 7, t = i - ci * 7;
    wt[((size_t)c * KW + t) * CIN + ci] = f2bf(vo[i] * scale);
  }
}

// ---------------------------------------------------------------------------
// prep 2: weight folds.
//  z=0: gwb[d][c] = 0.0625 * sum_a Wk[a][d]*Wq[a][c]   (Wq=qw[0:256], Wk=qw[256:512])
//  z=1: mpv[o][c] =          sum_a Wp[o][a]*Wv[a][c]   (Wv=qw[512:768])
// ---------------------------------------------------------------------------
__global__ __launch_bounds__(256) void prep_fold(
    const float* __restrict__ qw, const float* __restrict__ pw,
    u16* __restrict__ gwb, u16* __restrict__ mpv)
{
  const int z = blockIdx.z;
  const int d0 = blockIdx.y * 64, c0 = blockIdx.x * 64;
  const int tid = threadIdx.x;
  const int tx = tid & 15, ty = tid >> 4;
  __shared__ float As[16][68], Bs[16][68];
  float acc[4][4] = {};
  const int idx = tid * 4;
  const int kk4 = idx >> 6, cc4 = idx & 63;
  const int lm = idx >> 4, lk = idx & 15;

  for (int k0 = 0; k0 < 256; k0 += 16) {
    if (z == 0) {
      *(float4*)&As[kk4][cc4] = *(const float4*)(qw + (size_t)(256 + k0 + kk4) * 256 + d0 + cc4);
      *(float4*)&Bs[kk4][cc4] = *(const float4*)(qw + (size_t)(k0 + kk4) * 256 + c0 + cc4);
    } else {
      const float4 va = *(const float4*)(pw + (size_t)(d0 + lm) * 256 + k0 + lk);
      As[lk + 0][lm] = va.x; As[lk + 1][lm] = va.y; As[lk + 2][lm] = va.z; As[lk + 3][lm] = va.w;
      *(float4*)&Bs[kk4][cc4] = *(const float4*)(qw + (size_t)(512 + k0 + kk4) * 256 + c0 + cc4);
    }
    __syncthreads();
#pragma unroll
    for (int kk = 0; kk < 16; ++kk) {
      const float4 a = *(const float4*)&As[kk][ty * 4];
      const float4 bb = *(const float4*)&Bs[kk][tx * 4];
      const float av[4] = {a.x, a.y, a.z, a.w}, bv[4] = {bb.x, bb.y, bb.z, bb.w};
#pragma unroll
      for (int i = 0; i < 4; ++i)
#pragma unroll
        for (int j = 0; j < 4; ++j) acc[i][j] += av[i] * bv[j];
    }
    __syncthreads();
  }
  u16* dst = z ? mpv : gwb;
  const float scale = z ? 1.f : 0.0625f;
#pragma unroll
  for (int i = 0; i < 4; ++i) {
    const int d = d0 + ty * 4 + i;
#pragma unroll
    for (int j = 0; j < 4; ++j)
      dst[(size_t)d * 256 + c0 + tx * 4 + j] = f2bf(acc[i][j] * scale);
  }
}

// ---------------------------------------------------------------------------
// prep 3: bias folds + dw cast.
// params layout (f32): u[0:256], w[256:512], bpv[512:768], c0 at [768]
//  u[d]=0.0625*sum_a bq[a]Wk[a][d]; w[c]=0.0625*sum_a Wq[a][c]bk[a];
//  bpv[o]=sum_a Wp[o][a]bv[a] + pb[o]; c0=0.0625*bq.bk
// ---------------------------------------------------------------------------
__global__ __launch_bounds__(256) void fold_misc(
    const float* __restrict__ qw, const float* __restrict__ qb,
    const float* __restrict__ pw, const float* __restrict__ pb,
    const float* __restrict__ dw, float* __restrict__ params,
    u16* __restrict__ dwb)
{
  const int bid = blockIdx.x, tid = threadIdx.x;
  if (bid >= 258) {                       // dw cast: 128 blocks x 256 = 32768
    const int i = (bid - 258) * 256 + tid;
    dwb[i] = f2bf(dw[i]);
    return;
  }
  if (bid >= 2) {                         // bpv[o], o = bid-2, block-reduce
    const int o = bid - 2;
    float part = pw[(size_t)o * 256 + tid] * qb[512 + tid];
#pragma unroll
    for (int off = 1; off < 64; off <<= 1) part += __shfl_xor(part, off);
    __shared__ float red[4];
    if ((tid & 63) == 0) red[tid >> 6] = part;
    __syncthreads();
    if (tid == 0) params[512 + o] = red[0] + red[1] + red[2] + red[3] + pb[o];
    return;
  }
  if (bid == 1) {                         // w[c]
    float s0 = 0, s1 = 0, s2 = 0, s3 = 0;
    for (int a = 0; a < 256; a += 4) {
      s0 += qw[(size_t)(a + 0) * 256 + tid] * qb[256 + a + 0];
      s1 += qw[(size_t)(a + 1) * 256 + tid] * qb[256 + a + 1];
      s2 += qw[(size_t)(a + 2) * 256 + tid] * qb[256 + a + 2];
      s3 += qw[(size_t)(a + 3) * 256 + tid] * qb[256 + a + 3];
    }
    params[256 + tid] = 0.0625f * (s0 + s1 + s2 + s3);
    return;
  }
  // bid == 0: u[d] + c0
  float s0 = 0, s1 = 0, s2 = 0, s3 = 0;
  for (int a = 0; a < 256; a += 4) {
    s0 += qw[(size_t)(256 + a + 0) * 256 + tid] * qb[a + 0];
    s1 += qw[(size_t)(256 + a + 1) * 256 + tid] * qb[a + 1];
    s2 += qw[(size_t)(256 + a + 2) * 256 + tid] * qb[a + 2];
    s3 += qw[(size_t)(256 + a + 3) * 256 + tid] * qb[a + 3];
  }
  params[tid] = 0.0625f * (s0 + s1 + s2 + s3);
  float part = qb[tid] * qb[256 + tid];
#pragma unroll
  for (int off = 1; off < 64; off <<= 1) part += __shfl_xor(part, off);
  __shared__ float red2[4];
  if ((tid & 63) == 0) red2[tid >> 6] = part;
  __syncthreads();
  if (tid == 0) params[768] = 0.0625f * (red2[0] + red2[1] + red2[2] + red2[3]);
}

// ---------------------------------------------------------------------------
// prep 4: zero xT pads; zero h pads; fill g pads with u (h_pad=0 => g'=u)
// ---------------------------------------------------------------------------
__global__ __launch_bounds__(256) void zero_fill2(
    u16* __restrict__ xT, u16* __restrict__ h, u16* __restrict__ g,
    const float* __restrict__ params)
{
  const int idx = blockIdx.x * 256 + threadIdx.x;   // < 61440
  if (idx < 12288) {
    const int b = idx / 1536, r = idx - b * 1536;
    xT[(size_t)b * L2V * CIN + r] = 0;
  } else if (idx < 36864) {
    const int k = idx - 12288;
    const int b = k / 3072, r = k - b * 3072;
    h[(size_t)b * L2V * COUT + r] = 0;
  } else {
    const int k = idx - 36864;
    const int b = k / 3072, r = k - b * 3072;
    g[(size_t)b * L2V * COUT + r] = f2bf(params[r & 255]);
  }
}

// ---------------------------------------------------------------------------
// prep 5: transpose x[b][ci][p] f32 -> xT[b][12+p][ci] bf16
// ---------------------------------------------------------------------------
__global__ __launch_bounds__(256) void xpose(const float* __restrict__ x, u16* __restrict__ xT)
{
  const int b = blockIdx.y, p0 = blockIdx.x * 64;
  const int tx = threadIdx.x & 15, ty = threadIdx.x >> 4;
  const int p = p0 + ty * 4;
  const float* xb = x + (size_t)b * CIN * LEN;
  u16* xTb = xT + (size_t)b * L2V * CIN + (size_t)(PADW + p) * CIN;
#pragma unroll
  for (int half = 0; half < 2; ++half) {
    const int ci0 = half * 64 + tx * 4;
    float r[4][4];
#pragma unroll
    for (int i = 0; i < 4; ++i)
      *(float4*)r[i] = *(const float4*)(xb + (size_t)(ci0 + i) * LEN + p);
#pragma unroll
    for (int j = 0; j < 4; ++j)
      *(ushort4*)(xTb + (size_t)j * CIN + ci0) =
          make_ushort4(f2bf(r[0][j]), f2bf(r[1][j]), f2bf(r[2][j]), f2bf(r[3][j]));
  }
}

// ---------------------------------------------------------------------------
// FUSED conv + g-GEMM.  128 positions x 256 out per block, 8 waves (64x64).
// Phase A: h tile in LDS (28 k-steps) -> also coalesced copy to HBM h.
// Phase B: g' = h @ gwb^T + u  (8 k-steps, K=256) -> HBM g.
// Triple-buffered gll staging, raw barriers, counted vmcnt (round-11 ledger).
// ---------------------------------------------------------------------------
__global__ __launch_bounds__(512, 2) void conv_g_fused(
    const u16* __restrict__ wt, const u16* __restrict__ xT,
    const float* __restrict__ c1b, const u16* __restrict__ gwb,
    const float* __restrict__ params, u16* __restrict__ hout,
    u16* __restrict__ gout)
{
  const int b = blockIdx.y;
  const int p0 = blockIdx.x * PTILE;
  const int tid = threadIdx.x;
  const int w = tid >> 6, lane = tid & 63;
  const int l15 = lane & 15, kg = lane >> 4;
  const int wA = w >> 1, wB = w & 1;

  __shared__ u16 hA[PTILE * 256];   // 64 KB resident h tile (chunk-swizzled)
  __shared__ u16 pool[40960];       // 80 KB staging pool

  const u16* xTb = xT + (size_t)b * L2V * CIN + (size_t)p0 * CIN;

  v4f acc[4][4];
#pragma unroll
  for (int i = 0; i < 4; ++i)
#pragma unroll
    for (int j = 0; j < 4; ++j) acc[i][j] = (v4f){0.f, 0.f, 0.f, 0.f};

  // ---------------- phase A: conv, K = 896 (28 slabs of 32) ----------------
  auto stageA = [&](int s, int buf) {
    const int t = s >> 2, ci0 = (s & 3) << 5;
    u16* dst = pool + buf * 12288;
#pragma unroll
    for (int i = 0; i < 2; ++i) {
      const int cidx = i * 512 + tid;
      const int row = cidx >> 2, ch = cidx & 3;
      gll16(wt + (size_t)row * KCONV + t * CIN + ci0 + ((ch ^ KEY3(row)) << 3),
            (void*)(dst + cidx * 8));
    }
    {
      const int row = tid >> 2, ch = tid & 3;
      gll16(xTb + (size_t)(2 * t + row) * CIN + ci0 + ((ch ^ KEY3(row)) << 3),
            (void*)(dst + 8192 + tid * 8));
    }
  };

  stageA(0, 0);
  stageA(1, 1);

#pragma unroll
  for (int s = 0; s < 28; ++s) {
    if (s < 27) wait_vm(3); else wait_vm(0);
    BARRIER()
    if (s < 26) stageA(s + 2, (s + 2) % 3);
    const u16* wbuf = pool + (s % 3) * 12288;
    const u16* xbuf = wbuf + 8192;
    v8s a[4], bb[4];
#pragma unroll
    for (int f = 0; f < 4; ++f) {
      const int c = wA * 64 + f * 16 + l15;
      a[f] = *(const v8s*)&wbuf[c * 32 + ((kg ^ KEY3(c)) << 3)];
      const int p = wB * 64 + f * 16 + l15;
      bb[f] = *(const v8s*)&xbuf[p * 32 + ((kg ^ KEY3(p)) << 3)];
    }
    MFMA16(acc, a, bb)
  }

  // conv epilogue: bias+relu -> hA (chunk-swizzled: chunk' = chunk ^ (p&7))
#pragma unroll
  for (int fi = 0; fi < 4; ++fi) {
    const int cb = wA * 64 + fi * 16 + kg * 4;
    const float4 bv = *(const float4*)(c1b + cb);
    const int ch32 = cb >> 3, off = cb & 7;
#pragma unroll
    for (int fj = 0; fj < 4; ++fj) {
      const int p = wB * 64 + fj * 16 + l15;
      *(ushort4*)&hA[p * 256 + ((ch32 ^ (p & 7)) << 3) + off] = make_ushort4(
          f2bf(fmaxf(acc[fi][fj][0] + bv.x, 0.f)),
          f2bf(fmaxf(acc[fi][fj][1] + bv.y, 0.f)),
          f2bf(fmaxf(acc[fi][fj][2] + bv.z, 0.f)),
          f2bf(fmaxf(acc[fi][fj][3] + bv.w, 0.f)));
      acc[fi][fj] = (v4f){0.f, 0.f, 0.f, 0.f};
    }
  }
  LGKM0();
  BARRIER()   // hA complete; read-only from here on

  // h -> HBM, fully coalesced (8 x int4 per thread)
  const size_t mg0h = (size_t)b * L2V + PADW + p0;
#pragma unroll
  for (int i = 0; i < 8; ++i) {
    const int chunk = i * 512 + tid;            // 4096 chunks of 16B
    const int p = chunk >> 5, ci = chunk & 31;
    const int4 vv = *(const int4*)&hA[p * 256 + ((ci ^ (p & 7)) << 3)];
    *(int4*)(hout + (mg0h + p) * COUT + ci * 8) = vv;
  }

  // ---------------- phase B: g-GEMM, K = 256 (8 slabs of 32) ---------------
  auto stageB = [&](int s, int buf) {
    u16* dst = pool + buf * 8192;
#pragma unroll
    for (int i = 0; i < 2; ++i) {
      const int cidx = i * 512 + tid;
      const int row = cidx >> 2, ch = cidx & 3;
      gll16(gwb + (size_t)row * COUT + (s << 5) + ((ch ^ KEY3(row)) << 3),
            (void*)(dst + cidx * 8));
    }
  };
  stageB(0, 0);
  stageB(1, 1);

#pragma unroll
  for (int s = 0; s < 8; ++s) {
    if (s < 7) wait_vm(2); else wait_vm(0);
    BARRIER()
    if (s < 6) stageB(s + 2, (s + 2) % 3);
    const u16* nbuf = pool + (s % 3) * 8192;
    v8s a[4], bb[4];
#pragma unroll
    for (int f = 0; f < 4; ++f) {
      const int n = wA * 64 + f * 16 + l15;
      a[f] = *(const v8s*)&nbuf[n * 32 + ((kg ^ KEY3(n)) << 3)];
      const int m = wB * 64 + f * 16 + l15;
      bb[f] = *(const v8s*)&hA[m * 256 + ((((s << 2) + kg) ^ (m & 7)) << 3)];
    }
    MFMA16(acc, a, bb)
  }

  // g epilogue: +u, -> T transpose buffer, coalesced stores (two 128-d halves)
  u16* T = pool + 24576;
#pragma unroll
  for (int h2 = 0; h2 < 2; ++h2) {
    if ((wA >> 1) == h2) {
#pragma unroll
      for (int fi = 0; fi < 4; ++fi) {
        const int jj = (wA & 1) * 64 + fi * 16 + kg * 4;   // d within half
        const float4 bv = *(const float4*)(params + h2 * 128 + jj);
        const int jc = jj >> 3, joff = jj & 7;
#pragma unroll
        for (int fj = 0; fj < 4; ++fj) {
          const int m = wB * 64 + fj * 16 + l15;
          *(ushort4*)&T[m * 128 + ((jc ^ (m & 15)) << 3) + joff] = make_ushort4(
              f2bf(acc[fi][fj][0] + bv.x), f2bf(acc[fi][fj][1] + bv.y),
              f2bf(acc[fi][fj][2] + bv.z), f2bf(acc[fi][fj][3] + bv.w));
        }
      }
    }
    LGKM0();
    BARRIER()
#pragma unroll
    for (int i2 = 0; i2 < 4; ++i2) {
      const int chunk = i2 * 512 + tid;     // 2048 chunks
      const int m = chunk >> 4, j16 = chunk & 15;
      const int4 vv = *(const int4*)&T[m * 128 + ((j16 ^ (m & 15)) << 3)];
      *(int4*)(gout + (mg0h + m) * COUT + h2 * 128 + j16 * 8) = vv;
    }
    LGKM0();
    BARRIER()
  }
}

// ---------------------------------------------------------------------------
// Attention v2 (folded): one wave per (b,j); lane owns 4 channels.
//  e = h_j.w + c0;  sc[t] = g'_j.h_pos + e + rpb;  s_j = sum_t a_t h_pos
// ---------------------------------------------------------------------------
__global__ __launch_bounds__(256) void attn_v2(
    const u16* __restrict__ h, const u16* __restrict__ g,
    const float* __restrict__ params, const float* __restrict__ rpb,
    u16* __restrict__ sout)
{
  const int wid = (blockIdx.x << 2) + (threadIdx.x >> 6);
  const int lane = threadIdx.x & 63;
  const int b = wid >> 12;
  const int j = wid & 4095;
  const int r = j & 1, ii = j >> 1;
  int start = ii - 3;
  start = start < 0 ? 0 : start;
  start = start > 2047 ? 2047 : start;

  const u16* hb = h + (size_t)b * L2V * COUT;
  const u16* gb = g + (size_t)b * L2V * COUT;

  const ushort4 gv = *(const ushort4*)(gb + (size_t)j * COUT + 4 * lane);
  const float g0 = bf2f(gv.x), g1 = bf2f(gv.y), g2 = bf2f(gv.z), g3 = bf2f(gv.w);
  const ushort4 hj = *(const ushort4*)(hb + (size_t)j * COUT + 4 * lane);
  const float4 wv = *(const float4*)(params + 256 + 4 * lane);
  float e = bf2f(hj.x) * wv.x + bf2f(hj.y) * wv.y +
            bf2f(hj.z) * wv.z + bf2f(hj.w) * wv.w;
#pragma unroll
  for (int o = 1; o < 64; o <<= 1) e += __shfl_xor(e, o);
  e += params[768];

  float hp[7][4];
  float sc[7];
  float mx = -1e30f;
#pragma unroll
  for (int t = 0; t < 7; ++t) {
    const int pos = r + 2 * (start + t);
    const ushort4 hv = *(const ushort4*)(hb + (size_t)pos * COUT + 4 * lane);
    hp[t][0] = bf2f(hv.x); hp[t][1] = bf2f(hv.y);
    hp[t][2] = bf2f(hv.z); hp[t][3] = bf2f(hv.w);
    float s = g0 * hp[t][0] + g1 * hp[t][1] + g2 * hp[t][2] + g3 * hp[t][3];
#pragma unroll
    for (int o = 1; o < 64; o <<= 1) s += __shfl_xor(s, o);
    s += e + rpb[start + t - ii + 6];
    sc[t] = s;
    mx = fmaxf(mx, s);
  }
  float sum = 0.f;
#pragma unroll
  for (int t = 0; t < 7; ++t) { sc[t] = __expf(sc[t] - mx); sum += sc[t]; }
  const float inv = 1.f / sum;

  float a0 = 0.f, a1 = 0.f, a2 = 0.f, a3 = 0.f;
#pragma unroll
  for (int t = 0; t < 7; ++t) {
    const float wgt = sc[t] * inv;
    a0 += wgt * hp[t][0]; a1 += wgt * hp[t][1];
    a2 += wgt * hp[t][2]; a3 += wgt * hp[t][3];
  }
  *(ushort4*)(sout + ((size_t)(b * LEN + j)) * COUT + 4 * lane) =
      make_ushort4(f2bf(a0), f2bf(a1), f2bf(a2), f2bf(a3));
}

// ---------------------------------------------------------------------------
// fused proj(+folded v) + ds residual + double relu, gll-staged 128x128 tile.
// reads s (attn out over h), weights mpv, bias bpv.  (structure = round 9/11)
// ---------------------------------------------------------------------------
__global__ __launch_bounds__(256, 2) void projds_gll(
    const u16* __restrict__ ao, const u16* __restrict__ pwb,
    const float* __restrict__ pb, const u16* __restrict__ xT,
    const u16* __restrict__ dwb, const float* __restrict__ db,
    float* __restrict__ out)
{
  const int b = blockIdx.z;
  const int l0 = blockIdx.x * 128, o0 = blockIdx.y * 128;
  const int tid = threadIdx.x;
  const int w = tid >> 6, lane = tid & 63;
  const int l15 = lane & 15, kg = lane >> 4;
  const int wr = w >> 1, wc = w & 1;

  __shared__ u16 sX[2][128 * 32];
  __shared__ u16 sW[2][128 * 32];

  const int arow = tid >> 2, ach = tid & 3;
  const int akey = KEY3(arow);
  const u16* aob = ao + (size_t)b * LEN * COUT;
  const u16* xTb = xT + ((size_t)b * L2V + PADW) * CIN;

  auto stage1 = [&](int s, int buf) {
#pragma unroll
    for (int i = 0; i < 2; ++i) {
      const int row = i * 64 + arow;
      const int sl = (ach ^ akey) << 3;
      gll16(aob + (size_t)(l0 + row) * COUT + (s << 5) + sl,
            (void*)&sX[buf][(i * 256 + tid) * 8]);
      gll16(pwb + (size_t)(o0 + row) * COUT + (s << 5) + sl,
            (void*)&sW[buf][(i * 256 + tid) * 8]);
    }
  };
  auto stage2 = [&](int s, int buf) {
#pragma unroll
    for (int i = 0; i < 2; ++i) {
      const int row = i * 64 + arow;
      const int sl = (ach ^ akey) << 3;
      gll16(xTb + (size_t)(l0 + row) * CIN + (s << 5) + sl,
            (void*)&sX[buf][(i * 256 + tid) * 8]);
      gll16(dwb + (size_t)(o0 + row) * CIN + (s << 5) + sl,
            (void*)&sW[buf][(i * 256 + tid) * 8]);
    }
  };

  v4f acc[4][4];
#pragma unroll
  for (int i = 0; i < 4; ++i)
#pragma unroll
    for (int j = 0; j < 4; ++j) acc[i][j] = (v4f){0.f, 0.f, 0.f, 0.f};

  stage1(0, 0);
  __syncthreads();
  for (int ss = 0; ss < 12; ++ss) {
    const int buf = ss & 1;
    if (ss < 7) stage1(ss + 1, buf ^ 1);
    else if (ss < 11) stage2(ss - 7, buf ^ 1);
    v8s a[4], bb[4];
#pragma unroll
    for (int f = 0; f < 4; ++f) {
      const int lr = wr * 64 + f * 16 + l15;
      a[f] = *(const v8s*)&sX[buf][lr * 32 + ((kg ^ KEY3(lr)) << 3)];
      const int orr = wc * 64 + f * 16 + l15;
      bb[f] = *(const v8s*)&sW[buf][orr * 32 + ((kg ^ KEY3(orr)) << 3)];
    }
#pragma unroll
    for (int fi_ = 0; fi_ < 4; ++fi_)
#pragma unroll
      for (int fj_ = 0; fj_ < 4; ++fj_)
        acc[fi_][fj_] = __builtin_amdgcn_mfma_f32_16x16x32_bf16(
            a[fi_], bb[fj_], acc[fi_][fj_], 0, 0, 0);
    if (ss == 7) {
#pragma unroll
      for (int fj = 0; fj < 4; ++fj) {
        const float pbv = pb[o0 + wc * 64 + fj * 16 + l15];
#pragma unroll
        for (int fi = 0; fi < 4; ++fi)
#pragma unroll
          for (int jj = 0; jj < 4; ++jj)
            acc[fi][fj][jj] = fmaxf(acc[fi][fj][jj] + pbv, 0.f);
      }
    }
    __syncthreads();
  }

#pragma unroll
  for (int fj = 0; fj < 4; ++fj) {
    const int o = o0 + wc * 64 + fj * 16 + l15;
    const float dbv = db[o];
    float* orow = out + ((size_t)(b * COUT + o)) * LEN;
#pragma unroll
    for (int fi = 0; fi < 4; ++fi) {
      const int lb = l0 + wr * 64 + fi * 16 + kg * 4;
      float v0 = acc[fi][fj][0] + dbv; v0 = v0 > 0.f ? v0 : 0.f;
      float v1 = acc[fi][fj][1] + dbv; v1 = v1 > 0.f ? v1 : 0.f;
      float v2 = acc[fi][fj][2] + dbv; v2 = v2 > 0.f ? v2 : 0.f;
      float v3 = acc[fi][fj][3] + dbv; v3 = v3 > 0.f ? v3 : 0.f;
      *(float4*)(orow + lb) = make_float4(v0, v1, v2, v3);
    }
  }
}

// ---------------------------------------------------------------------------
extern "C" void kernel_launch(void* const* d_in, const int* in_sizes, int n_in,
                              void* d_out, int out_size, void* d_ws, size_t ws_size,
                              hipStream_t stream)
{
  (void)in_sizes; (void)n_in; (void)out_size; (void)ws_size;
  const float* x   = (const float*)d_in[0];
  const float* c1v = (const float*)d_in[1];
  const float* c1g = (const float*)d_in[2];
  const float* c1b = (const float*)d_in[3];
  const float* qw  = (const float*)d_in[4];
  const float* qb  = (const float*)d_in[5];
  const float* rpb = (const float*)d_in[6];
  const float* pw  = (const float*)d_in[7];
  const float* pb  = (const float*)d_in[8];
  const float* dw  = (const float*)d_in[9];
  const float* db  = (const float*)d_in[10];
  float* out = (float*)d_out;

  char* ws = (char*)d_ws;
  u16*   wt     = (u16*)(ws);                    //   458,752 B
  u16*   gwb    = (u16*)(ws + 458752);           //   131,072 B
  u16*   mpv    = (u16*)(ws + 589824);           //   131,072 B
  u16*   dwb    = (u16*)(ws + 720896);           //    65,536 B
  float* params = (float*)(ws + 786432);         //     4,096 B (u,w,bpv,c0)
  u16*   xT     = (u16*)(ws + 1048576);          // 8,413,184 B
  u16*   h      = (u16*)(ws + 9461760);          // 16,826,368 B
  u16*   g      = (u16*)(ws + 26288128);         // 16,826,368 B
  u16*   s      = (u16*)(ws + 43114496);         // 16,777,216 B (ends ~60 MB)

  prep_wn<<<COUT, 256, 0, stream>>>(c1v, c1g, wt);
  prep_fold<<<dim3(4, 4, 2), 256, 0, stream>>>(qw, pw, gwb, mpv);
  fold_misc<<<386, 256, 0, stream>>>(qw, qb, pw, pb, dw, params, dwb);
  zero_fill2<<<240, 256, 0, stream>>>(xT, h, g, params);
  xpose<<<dim3(LEN / 64, BATCH), 256, 0, stream>>>(x, xT);
  conv_g_fused<<<dim3(LEN / PTILE, BATCH), 512, 0, stream>>>(wt, xT, c1b, gwb, params, h, g);
  attn_v2<<<(BATCH * LEN) / 4, 256, 0, stream>>>(h, g, params, rpb, s);
  projds_gll<<<dim3(LEN / 128, COUT / 128, BATCH), 256, 0, stream>>>(
      s, mpv, params + 512, xT, dwb, db, out);
}

// Round 13
// 101.984 us; speedup vs baseline: 1.1011x; 1.1011x over previous
//
#include <hip/hip_runtime.h>
#include <math.h>

#define KW 7
#define PADW 12
#define BATCH 8
#define CIN 128
#define COUT 256
#define LEN 4096
#define L2V 4108
#define KCONV 896
#define PTILE 128

typedef unsigned short u16;
typedef short v8s __attribute__((ext_vector_type(8)));
typedef float v4f __attribute__((ext_vector_type(4)));

// 2-bit chunk swizzle key from row bits 0..2 (keeps ds_read_b128 <=2-way)
#define KEY3(r) ((((r) & 3) ^ (((r) >> 2) & 1)))

__device__ __forceinline__ u16 f2bf(float f) {
  unsigned int x = __float_as_uint(f);
  x += 0x7fffu + ((x >> 16) & 1u);
  return (u16)(x >> 16);
}
__device__ __forceinline__ float bf2f(u16 u) {
  return __uint_as_float(((unsigned int)u) << 16);
}

__device__ __forceinline__ void gll16(const void* g, void* l) {
  __builtin_amdgcn_global_load_lds(
      (const __attribute__((address_space(1))) void*)g,
      (__attribute__((address_space(3))) void*)l, 16, 0, 0);
}

__device__ __forceinline__ void wait_vm(int n) {
  switch (n) {
    case 0: asm volatile("s_waitcnt vmcnt(0)" ::: "memory"); break;
    case 2: asm volatile("s_waitcnt vmcnt(2)" ::: "memory"); break;
    case 3: asm volatile("s_waitcnt vmcnt(3)" ::: "memory"); break;
  }
}
#define LGKM0()  asm volatile("s_waitcnt lgkmcnt(0)" ::: "memory")
#define BARRIER() { __builtin_amdgcn_s_barrier(); asm volatile("" ::: "memory"); }

#define MFMA16(ACC, AA, BB)                                                    \
  { _Pragma("unroll") for (int fi_ = 0; fi_ < 4; ++fi_)                        \
    _Pragma("unroll") for (int fj_ = 0; fj_ < 4; ++fj_)                        \
      ACC[fi_][fj_] = __builtin_amdgcn_mfma_f32_16x16x32_bf16(                 \
          AA[fi_], BB[fj_], ACC[fi_][fj_], 0, 0, 0); }

// ---------------------------------------------------------------------------
// prep 1: weight norm -> wt[c][t][ci] bf16  (k = t*128+ci contiguous per c)
// ---------------------------------------------------------------------------
__global__ __launch_bounds__(256) void prep_wn(
    const float* __restrict__ v, const float* __restrict__ g,
    u16* __restrict__ wt)
{
  const int c = blockIdx.x;
  const float* vo = v + (size_t)c * (CIN * KW);
  float s = 0.f;
  for (int i = threadIdx.x; i < CIN * KW; i += 256) { float t = vo[i]; s += t * t; }
#pragma unroll
  for (int off = 1; off < 64; off <<= 1) s += __shfl_xor(s, off);
  __shared__ float red[4];
  if ((threadIdx.x & 63) == 0) red[threadIdx.x >> 6] = s;
  __syncthreads();
  const float tot = red[0] + red[1] + red[2] + red[3];
  const float scale = g[c] / sqrtf(tot);
  for (int i = threadIdx.x; i < CIN * KW; i += 256) {
    const int ci = i / 7, t = i - ci * 7;
    wt[((size_t)c * KW + t) * CIN + ci] = f2bf(vo[i] * scale);
  }
}

// ---------------------------------------------------------------------------
// prep 2: weight folds.
//  z=0: gwb[d][c] = 0.0625 * sum_a Wk[a][d]*Wq[a][c]
//  z=1: mpv[o][c] =          sum_a Wp[o][a]*Wv[a][c]
// ---------------------------------------------------------------------------
__global__ __launch_bounds__(256) void prep_fold(
    const float* __restrict__ qw, const float* __restrict__ pw,
    u16* __restrict__ gwb, u16* __restrict__ mpv)
{
  const int z = blockIdx.z;
  const int d0 = blockIdx.y * 64, c0 = blockIdx.x * 64;
  const int tid = threadIdx.x;
  const int tx = tid & 15, ty = tid >> 4;
  __shared__ float As[16][68], Bs[16][68];
  float acc[4][4] = {};
  const int idx = tid * 4;
  const int kk4 = idx >> 6, cc4 = idx & 63;
  const int lm = idx >> 4, lk = idx & 15;

  for (int k0 = 0; k0 < 256; k0 += 16) {
    if (z == 0) {
      *(float4*)&As[kk4][cc4] = *(const float4*)(qw + (size_t)(256 + k0 + kk4) * 256 + d0 + cc4);
      *(float4*)&Bs[kk4][cc4] = *(const float4*)(qw + (size_t)(k0 + kk4) * 256 + c0 + cc4);
    } else {
      const float4 va = *(const float4*)(pw + (size_t)(d0 + lm) * 256 + k0 + lk);
      As[lk + 0][lm] = va.x; As[lk + 1][lm] = va.y; As[lk + 2][lm] = va.z; As[lk + 3][lm] = va.w;
      *(float4*)&Bs[kk4][cc4] = *(const float4*)(qw + (size_t)(512 + k0 + kk4) * 256 + c0 + cc4);
    }
    __syncthreads();
#pragma unroll
    for (int kk = 0; kk < 16; ++kk) {
      const float4 a = *(const float4*)&As[kk][ty * 4];
      const float4 bb = *(const float4*)&Bs[kk][tx * 4];
      const float av[4] = {a.x, a.y, a.z, a.w}, bv[4] = {bb.x, bb.y, bb.z, bb.w};
#pragma unroll
      for (int i = 0; i < 4; ++i)
#pragma unroll
        for (int j = 0; j < 4; ++j) acc[i][j] += av[i] * bv[j];
    }
    __syncthreads();
  }
  u16* dst = z ? mpv : gwb;
  const float scale = z ? 1.f : 0.0625f;
#pragma unroll
  for (int i = 0; i < 4; ++i) {
    const int d = d0 + ty * 4 + i;
#pragma unroll
    for (int j = 0; j < 4; ++j)
      dst[(size_t)d * 256 + c0 + tx * 4 + j] = f2bf(acc[i][j] * scale);
  }
}

// ---------------------------------------------------------------------------
// prep 3: bias folds + dw cast.
// params layout (f32): u[0:256], (unused)[256:512], bpv[512:768]
// ---------------------------------------------------------------------------
__global__ __launch_bounds__(256) void fold_misc(
    const float* __restrict__ qw, const float* __restrict__ qb,
    const float* __restrict__ pw, const float* __restrict__ pb,
    const float* __restrict__ dw, float* __restrict__ params,
    u16* __restrict__ dwb)
{
  const int bid = blockIdx.x, tid = threadIdx.x;
  if (bid >= 258) {                       // dw cast
    const int i = (bid - 258) * 256 + tid;
    dwb[i] = f2bf(dw[i]);
    return;
  }
  if (bid >= 2) {                         // bpv[o], o = bid-2
    const int o = bid - 2;
    float part = pw[(size_t)o * 256 + tid] * qb[512 + tid];
#pragma unroll
    for (int off = 1; off < 64; off <<= 1) part += __shfl_xor(part, off);
    __shared__ float red[4];
    if ((tid & 63) == 0) red[tid >> 6] = part;
    __syncthreads();
    if (tid == 0) params[512 + o] = red[0] + red[1] + red[2] + red[3] + pb[o];
    return;
  }
  if (bid == 1) return;                   // (w fold no longer needed)
  // bid == 0: u[d]
  float s0 = 0, s1 = 0, s2 = 0, s3 = 0;
  for (int a = 0; a < 256; a += 4) {
    s0 += qw[(size_t)(256 + a + 0) * 256 + tid] * qb[a + 0];
    s1 += qw[(size_t)(256 + a + 1) * 256 + tid] * qb[a + 1];
    s2 += qw[(size_t)(256 + a + 2) * 256 + tid] * qb[a + 2];
    s3 += qw[(size_t)(256 + a + 3) * 256 + tid] * qb[a + 3];
  }
  params[tid] = 0.0625f * (s0 + s1 + s2 + s3);
}

// ---------------------------------------------------------------------------
// prep 4: zero xT pads; zero h pads; fill g pads with u
// ---------------------------------------------------------------------------
__global__ __launch_bounds__(256) void zero_fill2(
    u16* __restrict__ xT, u16* __restrict__ h, u16* __restrict__ g,
    const float* __restrict__ params)
{
  const int idx = blockIdx.x * 256 + threadIdx.x;   // < 61440
  if (idx < 12288) {
    const int b = idx / 1536, r = idx - b * 1536;
    xT[(size_t)b * L2V * CIN + r] = 0;
  } else if (idx < 36864) {
    const int k = idx - 12288;
    const int b = k / 3072, r = k - b * 3072;
    h[(size_t)b * L2V * COUT + r] = 0;
  } else {
    const int k = idx - 36864;
    const int b = k / 3072, r = k - b * 3072;
    g[(size_t)b * L2V * COUT + r] = f2bf(params[r & 255]);
  }
}

// ---------------------------------------------------------------------------
// prep 5: transpose x[b][ci][p] f32 -> xT[b][12+p][ci] bf16
// ---------------------------------------------------------------------------
__global__ __launch_bounds__(256) void xpose(const float* __restrict__ x, u16* __restrict__ xT)
{
  const int b = blockIdx.y, p0 = blockIdx.x * 64;
  const int tx = threadIdx.x & 15, ty = threadIdx.x >> 4;
  const int p = p0 + ty * 4;
  const float* xb = x + (size_t)b * CIN * LEN;
  u16* xTb = xT + (size_t)b * L2V * CIN + (size_t)(PADW + p) * CIN;
#pragma unroll
  for (int half = 0; half < 2; ++half) {
    const int ci0 = half * 64 + tx * 4;
    float r[4][4];
#pragma unroll
    for (int i = 0; i < 4; ++i)
      *(float4*)r[i] = *(const float4*)(xb + (size_t)(ci0 + i) * LEN + p);
#pragma unroll
    for (int j = 0; j < 4; ++j)
      *(ushort4*)(xTb + (size_t)j * CIN + ci0) =
          make_ushort4(f2bf(r[0][j]), f2bf(r[1][j]), f2bf(r[2][j]), f2bf(r[3][j]));
  }
}

// ---------------------------------------------------------------------------
// FUSED conv + g-GEMM (round-12 structure, unchanged).
// ---------------------------------------------------------------------------
__global__ __launch_bounds__(512, 2) void conv_g_fused(
    const u16* __restrict__ wt, const u16* __restrict__ xT,
    const float* __restrict__ c1b, const u16* __restrict__ gwb,
    const float* __restrict__ params, u16* __restrict__ hout,
    u16* __restrict__ gout)
{
  const int b = blockIdx.y;
  const int p0 = blockIdx.x * PTILE;
  const int tid = threadIdx.x;
  const int w = tid >> 6, lane = tid & 63;
  const int l15 = lane & 15, kg = lane >> 4;
  const int wA = w >> 1, wB = w & 1;

  __shared__ u16 hA[PTILE * 256];
  __shared__ u16 pool[40960];

  const u16* xTb = xT + (size_t)b * L2V * CIN + (size_t)p0 * CIN;

  v4f acc[4][4];
#pragma unroll
  for (int i = 0; i < 4; ++i)
#pragma unroll
    for (int j = 0; j < 4; ++j) acc[i][j] = (v4f){0.f, 0.f, 0.f, 0.f};

  auto stageA = [&](int s, int buf) {
    const int t = s >> 2, ci0 = (s & 3) << 5;
    u16* dst = pool + buf * 12288;
#pragma unroll
    for (int i = 0; i < 2; ++i) {
      const int cidx = i * 512 + tid;
      const int row = cidx >> 2, ch = cidx & 3;
      gll16(wt + (size_t)row * KCONV + t * CIN + ci0 + ((ch ^ KEY3(row)) << 3),
            (void*)(dst + cidx * 8));
    }
    {
      const int row = tid >> 2, ch = tid & 3;
      gll16(xTb + (size_t)(2 * t + row) * CIN + ci0 + ((ch ^ KEY3(row)) << 3),
            (void*)(dst + 8192 + tid * 8));
    }
  };

  stageA(0, 0);
  stageA(1, 1);

#pragma unroll
  for (int s = 0; s < 28; ++s) {
    if (s < 27) wait_vm(3); else wait_vm(0);
    BARRIER()
    if (s < 26) stageA(s + 2, (s + 2) % 3);
    const u16* wbuf = pool + (s % 3) * 12288;
    const u16* xbuf = wbuf + 8192;
    v8s a[4], bb[4];
#pragma unroll
    for (int f = 0; f < 4; ++f) {
      const int c = wA * 64 + f * 16 + l15;
      a[f] = *(const v8s*)&wbuf[c * 32 + ((kg ^ KEY3(c)) << 3)];
      const int p = wB * 64 + f * 16 + l15;
      bb[f] = *(const v8s*)&xbuf[p * 32 + ((kg ^ KEY3(p)) << 3)];
    }
    MFMA16(acc, a, bb)
  }

#pragma unroll
  for (int fi = 0; fi < 4; ++fi) {
    const int cb = wA * 64 + fi * 16 + kg * 4;
    const float4 bv = *(const float4*)(c1b + cb);
    const int ch32 = cb >> 3, off = cb & 7;
#pragma unroll
    for (int fj = 0; fj < 4; ++fj) {
      const int p = wB * 64 + fj * 16 + l15;
      *(ushort4*)&hA[p * 256 + ((ch32 ^ (p & 7)) << 3) + off] = make_ushort4(
          f2bf(fmaxf(acc[fi][fj][0] + bv.x, 0.f)),
          f2bf(fmaxf(acc[fi][fj][1] + bv.y, 0.f)),
          f2bf(fmaxf(acc[fi][fj][2] + bv.z, 0.f)),
          f2bf(fmaxf(acc[fi][fj][3] + bv.w, 0.f)));
      acc[fi][fj] = (v4f){0.f, 0.f, 0.f, 0.f};
    }
  }
  LGKM0();
  BARRIER()

  const size_t mg0h = (size_t)b * L2V + PADW + p0;
#pragma unroll
  for (int i = 0; i < 8; ++i) {
    const int chunk = i * 512 + tid;
    const int p = chunk >> 5, ci = chunk & 31;
    const int4 vv = *(const int4*)&hA[p * 256 + ((ci ^ (p & 7)) << 3)];
    *(int4*)(hout + (mg0h + p) * COUT + ci * 8) = vv;
  }

  auto stageB = [&](int s, int buf) {
    u16* dst = pool + buf * 8192;
#pragma unroll
    for (int i = 0; i < 2; ++i) {
      const int cidx = i * 512 + tid;
      const int row = cidx >> 2, ch = cidx & 3;
      gll16(gwb + (size_t)row * COUT + (s << 5) + ((ch ^ KEY3(row)) << 3),
            (void*)(dst + cidx * 8));
    }
  };
  stageB(0, 0);
  stageB(1, 1);

#pragma unroll
  for (int s = 0; s < 8; ++s) {
    if (s < 7) wait_vm(2); else wait_vm(0);
    BARRIER()
    if (s < 6) stageB(s + 2, (s + 2) % 3);
    const u16* nbuf = pool + (s % 3) * 8192;
    v8s a[4], bb[4];
#pragma unroll
    for (int f = 0; f < 4; ++f) {
      const int n = wA * 64 + f * 16 + l15;
      a[f] = *(const v8s*)&nbuf[n * 32 + ((kg ^ KEY3(n)) << 3)];
      const int m = wB * 64 + f * 16 + l15;
      bb[f] = *(const v8s*)&hA[m * 256 + ((((s << 2) + kg) ^ (m & 7)) << 3)];
    }
    MFMA16(acc, a, bb)
  }

  u16* T = pool + 24576;
#pragma unroll
  for (int h2 = 0; h2 < 2; ++h2) {
    if ((wA >> 1) == h2) {
#pragma unroll
      for (int fi = 0; fi < 4; ++fi) {
        const int jj = (wA & 1) * 64 + fi * 16 + kg * 4;
        const float4 bv = *(const float4*)(params + h2 * 128 + jj);
        const int jc = jj >> 3, joff = jj & 7;
#pragma unroll
        for (int fj = 0; fj < 4; ++fj) {
          const int m = wB * 64 + fj * 16 + l15;
          *(ushort4*)&T[m * 128 + ((jc ^ (m & 15)) << 3) + joff] = make_ushort4(
              f2bf(acc[fi][fj][0] + bv.x), f2bf(acc[fi][fj][1] + bv.y),
              f2bf(acc[fi][fj][2] + bv.z), f2bf(acc[fi][fj][3] + bv.w));
        }
      }
    }
    LGKM0();
    BARRIER()
#pragma unroll
    for (int i2 = 0; i2 < 4; ++i2) {
      const int chunk = i2 * 512 + tid;
      const int m = chunk >> 4, j16 = chunk & 15;
      const int4 vv = *(const int4*)&T[m * 128 + ((j16 ^ (m & 15)) << 3)];
      *(int4*)(gout + (mg0h + m) * COUT + h2 * 128 + j16 * 8) = vv;
    }
    LGKM0();
    BARRIER()
  }
}

// ---------------------------------------------------------------------------
// Attention v3: 4 queries per wave, 16 lanes per query (sub = lane>>4,
// cg = lane&15 owns 16 channels).  Per-query reduce = 4 intra-group shuffles.
// score[t] = g_j . h_pos + rpb  (the h_j-dependent term is softmax-invariant)
// out s_j = sum_t softmax_t * h_pos
// ---------------------------------------------------------------------------
__global__ __launch_bounds__(256) void attn_v3(
    const u16* __restrict__ h, const u16* __restrict__ g,
    const float* __restrict__ rpb, u16* __restrict__ sout)
{
  const int wid = blockIdx.x * 4 + (threadIdx.x >> 6);
  const int lane = threadIdx.x & 63;
  const int sub = lane >> 4, cg = lane & 15;
  const int q = wid * 4 + sub;              // global query 0..32767
  const int b = q >> 12;
  const int j = q & 4095;
  const int r = j & 1, ii = j >> 1;
  int start = ii - 3;
  start = start < 0 ? 0 : start;
  start = start > 2047 ? 2047 : start;

  const u16* hb = h + (size_t)b * L2V * COUT;
  const u16* gb = g + (size_t)b * L2V * COUT;
  const int co = cg * 16;

  // g fragment: 16 channels -> 16 floats
  float gf[16];
  {
    const int4 g0 = *(const int4*)(gb + (size_t)j * COUT + co);
    const int4 g1 = *(const int4*)(gb + (size_t)j * COUT + co + 8);
    const int gw[8] = {g0.x, g0.y, g0.z, g0.w, g1.x, g1.y, g1.z, g1.w};
#pragma unroll
    for (int i = 0; i < 8; ++i) {
      const unsigned int u = (unsigned int)gw[i];
      gf[2 * i]     = __uint_as_float(u << 16);
      gf[2 * i + 1] = __uint_as_float(u & 0xffff0000u);
    }
  }

  int4 hp0[7], hp1[7];
  float sc[7];
  float mx = -1e30f;
#pragma unroll
  for (int t = 0; t < 7; ++t) {
    const int pos = r + 2 * (start + t);
    const u16* hrow = hb + (size_t)pos * COUT + co;
    hp0[t] = *(const int4*)(hrow);
    hp1[t] = *(const int4*)(hrow + 8);
    const int hw[8] = {hp0[t].x, hp0[t].y, hp0[t].z, hp0[t].w,
                       hp1[t].x, hp1[t].y, hp1[t].z, hp1[t].w};
    float s = 0.f;
#pragma unroll
    for (int i = 0; i < 8; ++i) {
      const unsigned int u = (unsigned int)hw[i];
      s += gf[2 * i]     * __uint_as_float(u << 16);
      s += gf[2 * i + 1] * __uint_as_float(u & 0xffff0000u);
    }
    s += __shfl_xor(s, 1); s += __shfl_xor(s, 2);
    s += __shfl_xor(s, 4); s += __shfl_xor(s, 8);
    s += rpb[start + t - ii + 6];
    sc[t] = s;
    mx = fmaxf(mx, s);
  }
  float sum = 0.f;
#pragma unroll
  for (int t = 0; t < 7; ++t) { sc[t] = __expf(sc[t] - mx); sum += sc[t]; }
  const float inv = 1.f / sum;

  float acc[16];
#pragma unroll
  for (int i = 0; i < 16; ++i) acc[i] = 0.f;
#pragma unroll
  for (int t = 0; t < 7; ++t) {
    const float wgt = sc[t] * inv;
    const int hw[8] = {hp0[t].x, hp0[t].y, hp0[t].z, hp0[t].w,
                       hp1[t].x, hp1[t].y, hp1[t].z, hp1[t].w};
#pragma unroll
    for (int i = 0; i < 8; ++i) {
      const unsigned int u = (unsigned int)hw[i];
      acc[2 * i]     += wgt * __uint_as_float(u << 16);
      acc[2 * i + 1] += wgt * __uint_as_float(u & 0xffff0000u);
    }
  }
  u16* dst = sout + ((size_t)(b * LEN + j)) * COUT + co;
  ushort4 o0 = make_ushort4(f2bf(acc[0]), f2bf(acc[1]), f2bf(acc[2]), f2bf(acc[3]));
  ushort4 o1 = make_ushort4(f2bf(acc[4]), f2bf(acc[5]), f2bf(acc[6]), f2bf(acc[7]));
  ushort4 o2 = make_ushort4(f2bf(acc[8]), f2bf(acc[9]), f2bf(acc[10]), f2bf(acc[11]));
  ushort4 o3 = make_ushort4(f2bf(acc[12]), f2bf(acc[13]), f2bf(acc[14]), f2bf(acc[15]));
  *(ushort4*)(dst) = o0;  *(ushort4*)(dst + 4) = o1;
  *(ushort4*)(dst + 8) = o2; *(ushort4*)(dst + 12) = o3;
}

// ---------------------------------------------------------------------------
// fused proj(+folded v) + ds residual + double relu. (unchanged from r12)
// ---------------------------------------------------------------------------
__global__ __launch_bounds__(256, 2) void projds_gll(
    const u16* __restrict__ ao, const u16* __restrict__ pwb,
    const float* __restrict__ pb, const u16* __restrict__ xT,
    const u16* __restrict__ dwb, const float* __restrict__ db,
    float* __restrict__ out)
{
  const int b = blockIdx.z;
  const int l0 = blockIdx.x * 128, o0 = blockIdx.y * 128;
  const int tid = threadIdx.x;
  const int w = tid >> 6, lane = tid & 63;
  const int l15 = lane & 15, kg = lane >> 4;
  const int wr = w >> 1, wc = w & 1;

  __shared__ u16 sX[2][128 * 32];
  __shared__ u16 sW[2][128 * 32];

  const int arow = tid >> 2, ach = tid & 3;
  const int akey = KEY3(arow);
  const u16* aob = ao + (size_t)b * LEN * COUT;
  const u16* xTb = xT + ((size_t)b * L2V + PADW) * CIN;

  auto stage1 = [&](int s, int buf) {
#pragma unroll
    for (int i = 0; i < 2; ++i) {
      const int row = i * 64 + arow;
      const int sl = (ach ^ akey) << 3;
      gll16(aob + (size_t)(l0 + row) * COUT + (s << 5) + sl,
            (void*)&sX[buf][(i * 256 + tid) * 8]);
      gll16(pwb + (size_t)(o0 + row) * COUT + (s << 5) + sl,
            (void*)&sW[buf][(i * 256 + tid) * 8]);
    }
  };
  auto stage2 = [&](int s, int buf) {
#pragma unroll
    for (int i = 0; i < 2; ++i) {
      const int row = i * 64 + arow;
      const int sl = (ach ^ akey) << 3;
      gll16(xTb + (size_t)(l0 + row) * CIN + (s << 5) + sl,
            (void*)&sX[buf][(i * 256 + tid) * 8]);
      gll16(dwb + (size_t)(o0 + row) * CIN + (s << 5) + sl,
            (void*)&sW[buf][(i * 256 + tid) * 8]);
    }
  };

  v4f acc[4][4];
#pragma unroll
  for (int i = 0; i < 4; ++i)
#pragma unroll
    for (int j = 0; j < 4; ++j) acc[i][j] = (v4f){0.f, 0.f, 0.f, 0.f};

  stage1(0, 0);
  __syncthreads();
  for (int ss = 0; ss < 12; ++ss) {
    const int buf = ss & 1;
    if (ss < 7) stage1(ss + 1, buf ^ 1);
    else if (ss < 11) stage2(ss - 7, buf ^ 1);
    v8s a[4], bb[4];
#pragma unroll
    for (int f = 0; f < 4; ++f) {
      const int lr = wr * 64 + f * 16 + l15;
      a[f] = *(const v8s*)&sX[buf][lr * 32 + ((kg ^ KEY3(lr)) << 3)];
      const int orr = wc * 64 + f * 16 + l15;
      bb[f] = *(const v8s*)&sW[buf][orr * 32 + ((kg ^ KEY3(orr)) << 3)];
    }
#pragma unroll
    for (int fi_ = 0; fi_ < 4; ++fi_)
#pragma unroll
      for (int fj_ = 0; fj_ < 4; ++fj_)
        acc[fi_][fj_] = __builtin_amdgcn_mfma_f32_16x16x32_bf16(
            a[fi_], bb[fj_], acc[fi_][fj_], 0, 0, 0);
    if (ss == 7) {
#pragma unroll
      for (int fj = 0; fj < 4; ++fj) {
        const float pbv = pb[o0 + wc * 64 + fj * 16 + l15];
#pragma unroll
        for (int fi = 0; fi < 4; ++fi)
#pragma unroll
          for (int jj = 0; jj < 4; ++jj)
            acc[fi][fj][jj] = fmaxf(acc[fi][fj][jj] + pbv, 0.f);
      }
    }
    __syncthreads();
  }

#pragma unroll
  for (int fj = 0; fj < 4; ++fj) {
    const int o = o0 + wc * 64 + fj * 16 + l15;
    const float dbv = db[o];
    float* orow = out + ((size_t)(b * COUT + o)) * LEN;
#pragma unroll
    for (int fi = 0; fi < 4; ++fi) {
      const int lb = l0 + wr * 64 + fi * 16 + kg * 4;
      float v0 = acc[fi][fj][0] + dbv; v0 = v0 > 0.f ? v0 : 0.f;
      float v1 = acc[fi][fj][1] + dbv; v1 = v1 > 0.f ? v1 : 0.f;
      float v2 = acc[fi][fj][2] + dbv; v2 = v2 > 0.f ? v2 : 0.f;
      float v3 = acc[fi][fj][3] + dbv; v3 = v3 > 0.f ? v3 : 0.f;
      *(float4*)(orow + lb) = make_float4(v0, v1, v2, v3);
    }
  }
}

// ---------------------------------------------------------------------------
extern "C" void kernel_launch(void* const* d_in, const int* in_sizes, int n_in,
                              void* d_out, int out_size, void* d_ws, size_t ws_size,
                              hipStream_t stream)
{
  (void)in_sizes; (void)n_in; (void)out_size; (void)ws_size;
  const float* x   = (const float*)d_in[0];
  const float* c1v = (const float*)d_in[1];
  const float* c1g = (const float*)d_in[2];
  const float* c1b = (const float*)d_in[3];
  const float* qw  = (const float*)d_in[4];
  const float* qb  = (const float*)d_in[5];
  const float* rpb = (const float*)d_in[6];
  const float* pw  = (const float*)d_in[7];
  const float* pb  = (const float*)d_in[8];
  const float* dw  = (const float*)d_in[9];
  const float* db  = (const float*)d_in[10];
  float* out = (float*)d_out;

  char* ws = (char*)d_ws;
  u16*   wt     = (u16*)(ws);                    //   458,752 B
  u16*   gwb    = (u16*)(ws + 458752);           //   131,072 B
  u16*   mpv    = (u16*)(ws + 589824);           //   131,072 B
  u16*   dwb    = (u16*)(ws + 720896);           //    65,536 B
  float* params = (float*)(ws + 786432);         //     4,096 B (u,-,bpv)
  u16*   xT     = (u16*)(ws + 1048576);          // 8,413,184 B
  u16*   h      = (u16*)(ws + 9461760);          // 16,826,368 B
  u16*   g      = (u16*)(ws + 26288128);         // 16,826,368 B
  u16*   s      = (u16*)(ws + 43114496);         // 16,777,216 B

  prep_wn<<<COUT, 256, 0, stream>>>(c1v, c1g, wt);
  prep_fold<<<dim3(4, 4, 2), 256, 0, stream>>>(qw, pw, gwb, mpv);
  fold_misc<<<386, 256, 0, stream>>>(qw, qb, pw, pb, dw, params, dwb);
  zero_fill2<<<240, 256, 0, stream>>>(xT, h, g, params);
  xpose<<<dim3(LEN / 64, BATCH), 256, 0, stream>>>(x, xT);
  conv_g_fused<<<dim3(LEN / PTILE, BATCH), 512, 0, stream>>>(wt, xT, c1b, gwb, params, h, g);
  attn_v3<<<(BATCH * LEN) / 16, 256, 0, stream>>>(h, g, rpb, s);
  projds_gll<<<dim3(LEN / 128, COUT / 128, BATCH), 256, 0, stream>>>(
      s, mpv, params + 512, xT, dwb, db, out);
}

// Round 14
// 101.776 us; speedup vs baseline: 1.1034x; 1.0020x over previous
//
#include <hip/hip_runtime.h>
#include <math.h>

#define KW 7
#define PADW 12
#define BATCH 8
#define CIN 128
#define COUT 256
#define LEN 4096
#define L2V 4108
#define KCONV 896
#define PTILE 128

typedef unsigned short u16;
typedef short v8s __attribute__((ext_vector_type(8)));
typedef float v4f __attribute__((ext_vector_type(4)));

// 2-bit chunk swizzle key from row bits 0..2 (keeps ds_read_b128 <=2-way)
#define KEY3(r) ((((r) & 3) ^ (((r) >> 2) & 1)))

__device__ __forceinline__ u16 f2bf(float f) {
  unsigned int x = __float_as_uint(f);
  x += 0x7fffu + ((x >> 16) & 1u);
  return (u16)(x >> 16);
}
__device__ __forceinline__ float bf2f(u16 u) {
  return __uint_as_float(((unsigned int)u) << 16);
}

__device__ __forceinline__ void gll16(const void* g, void* l) {
  __builtin_amdgcn_global_load_lds(
      (const __attribute__((address_space(1))) void*)g,
      (__attribute__((address_space(3))) void*)l, 16, 0, 0);
}

__device__ __forceinline__ void wait_vm(int n) {
  switch (n) {
    case 0: asm volatile("s_waitcnt vmcnt(0)" ::: "memory"); break;
    case 2: asm volatile("s_waitcnt vmcnt(2)" ::: "memory"); break;
    case 3: asm volatile("s_waitcnt vmcnt(3)" ::: "memory"); break;
  }
}
#define LGKM0()  asm volatile("s_waitcnt lgkmcnt(0)" ::: "memory")
#define BARRIER() { __builtin_amdgcn_s_barrier(); asm volatile("" ::: "memory"); }

#define MFMA16(ACC, AA, BB)                                                    \
  { _Pragma("unroll") for (int fi_ = 0; fi_ < 4; ++fi_)                        \
    _Pragma("unroll") for (int fj_ = 0; fj_ < 4; ++fj_)                        \
      ACC[fi_][fj_] = __builtin_amdgcn_mfma_f32_16x16x32_bf16(                 \
          AA[fi_], BB[fj_], ACC[fi_][fj_], 0, 0, 0); }

// ---------------------------------------------------------------------------
// prep 1: weight norm -> wt[c][t][ci] bf16  (k = t*128+ci contiguous per c)
// ---------------------------------------------------------------------------
__global__ __launch_bounds__(256) void prep_wn(
    const float* __restrict__ v, const float* __restrict__ g,
    u16* __restrict__ wt)
{
  const int c = blockIdx.x;
  const float* vo = v + (size_t)c * (CIN * KW);
  float s = 0.f;
  for (int i = threadIdx.x; i < CIN * KW; i += 256) { float t = vo[i]; s += t * t; }
#pragma unroll
  for (int off = 1; off < 64; off <<= 1) s += __shfl_xor(s, off);
  __shared__ float red[4];
  if ((threadIdx.x & 63) == 0) red[threadIdx.x >> 6] = s;
  __syncthreads();
  const float tot = red[0] + red[1] + red[2] + red[3];
  const float scale = g[c] / sqrtf(tot);
  for (int i = threadIdx.x; i < CIN * KW; i += 256) {
    const int ci = i / 7, t = i - ci * 7;
    wt[((size_t)c * KW + t) * CIN + ci] = f2bf(vo[i] * scale);
  }
}

// ---------------------------------------------------------------------------
// prep 2: weight folds.
//  z=0: gwb[d][c] = 0.0625 * sum_a Wk[a][d]*Wq[a][c]
//  z=1: mpv[o][c] =          sum_a Wp[o][a]*Wv[a][c]
// ---------------------------------------------------------------------------
__global__ __launch_bounds__(256) void prep_fold(
    const float* __restrict__ qw, const float* __restrict__ pw,
    u16* __restrict__ gwb, u16* __restrict__ mpv)
{
  const int z = blockIdx.z;
  const int d0 = blockIdx.y * 64, c0 = blockIdx.x * 64;
  const int tid = threadIdx.x;
  const int tx = tid & 15, ty = tid >> 4;
  __shared__ float As[16][68], Bs[16][68];
  float acc[4][4] = {};
  const int idx = tid * 4;
  const int kk4 = idx >> 6, cc4 = idx & 63;
  const int lm = idx >> 4, lk = idx & 15;

  for (int k0 = 0; k0 < 256; k0 += 16) {
    if (z == 0) {
      *(float4*)&As[kk4][cc4] = *(const float4*)(qw + (size_t)(256 + k0 + kk4) * 256 + d0 + cc4);
      *(float4*)&Bs[kk4][cc4] = *(const float4*)(qw + (size_t)(k0 + kk4) * 256 + c0 + cc4);
    } else {
      const float4 va = *(const float4*)(pw + (size_t)(d0 + lm) * 256 + k0 + lk);
      As[lk + 0][lm] = va.x; As[lk + 1][lm] = va.y; As[lk + 2][lm] = va.z; As[lk + 3][lm] = va.w;
      *(float4*)&Bs[kk4][cc4] = *(const float4*)(qw + (size_t)(512 + k0 + kk4) * 256 + c0 + cc4);
    }
    __syncthreads();
#pragma unroll
    for (int kk = 0; kk < 16; ++kk) {
      const float4 a = *(const float4*)&As[kk][ty * 4];
      const float4 bb = *(const float4*)&Bs[kk][tx * 4];
      const float av[4] = {a.x, a.y, a.z, a.w}, bv[4] = {bb.x, bb.y, bb.z, bb.w};
#pragma unroll
      for (int i = 0; i < 4; ++i)
#pragma unroll
        for (int j = 0; j < 4; ++j) acc[i][j] += av[i] * bv[j];
    }
    __syncthreads();
  }
  u16* dst = z ? mpv : gwb;
  const float scale = z ? 1.f : 0.0625f;
#pragma unroll
  for (int i = 0; i < 4; ++i) {
    const int d = d0 + ty * 4 + i;
#pragma unroll
    for (int j = 0; j < 4; ++j)
      dst[(size_t)d * 256 + c0 + tx * 4 + j] = f2bf(acc[i][j] * scale);
  }
}

// ---------------------------------------------------------------------------
// prep 3: bias folds + dw cast.
// params layout (f32): u[0:256], (unused)[256:512], bpv[512:768]
// ---------------------------------------------------------------------------
__global__ __launch_bounds__(256) void fold_misc(
    const float* __restrict__ qw, const float* __restrict__ qb,
    const float* __restrict__ pw, const float* __restrict__ pb,
    const float* __restrict__ dw, float* __restrict__ params,
    u16* __restrict__ dwb)
{
  const int bid = blockIdx.x, tid = threadIdx.x;
  if (bid >= 258) {                       // dw cast
    const int i = (bid - 258) * 256 + tid;
    dwb[i] = f2bf(dw[i]);
    return;
  }
  if (bid >= 2) {                         // bpv[o], o = bid-2
    const int o = bid - 2;
    float part = pw[(size_t)o * 256 + tid] * qb[512 + tid];
#pragma unroll
    for (int off = 1; off < 64; off <<= 1) part += __shfl_xor(part, off);
    __shared__ float red[4];
    if ((tid & 63) == 0) red[tid >> 6] = part;
    __syncthreads();
    if (tid == 0) params[512 + o] = red[0] + red[1] + red[2] + red[3] + pb[o];
    return;
  }
  if (bid == 1) return;                   // (w fold no longer needed)
  // bid == 0: u[d]
  float s0 = 0, s1 = 0, s2 = 0, s3 = 0;
  for (int a = 0; a < 256; a += 4) {
    s0 += qw[(size_t)(256 + a + 0) * 256 + tid] * qb[a + 0];
    s1 += qw[(size_t)(256 + a + 1) * 256 + tid] * qb[a + 1];
    s2 += qw[(size_t)(256 + a + 2) * 256 + tid] * qb[a + 2];
    s3 += qw[(size_t)(256 + a + 3) * 256 + tid] * qb[a + 3];
  }
  params[tid] = 0.0625f * (s0 + s1 + s2 + s3);
}

// ---------------------------------------------------------------------------
// prep 4: zero xT pads; zero h pads; fill g pads with u
// ---------------------------------------------------------------------------
__global__ __launch_bounds__(256) void zero_fill2(
    u16* __restrict__ xT, u16* __restrict__ h, u16* __restrict__ g,
    const float* __restrict__ params)
{
  const int idx = blockIdx.x * 256 + threadIdx.x;   // < 61440
  if (idx < 12288) {
    const int b = idx / 1536, r = idx - b * 1536;
    xT[(size_t)b * L2V * CIN + r] = 0;
  } else if (idx < 36864) {
    const int k = idx - 12288;
    const int b = k / 3072, r = k - b * 3072;
    h[(size_t)b * L2V * COUT + r] = 0;
  } else {
    const int k = idx - 36864;
    const int b = k / 3072, r = k - b * 3072;
    g[(size_t)b * L2V * COUT + r] = f2bf(params[r & 255]);
  }
}

// ---------------------------------------------------------------------------
// prep 5: transpose x[b][ci][p] f32 -> xT[b][12+p][ci] bf16
// ---------------------------------------------------------------------------
__global__ __launch_bounds__(256) void xpose(const float* __restrict__ x, u16* __restrict__ xT)
{
  const int b = blockIdx.y, p0 = blockIdx.x * 64;
  const int tx = threadIdx.x & 15, ty = threadIdx.x >> 4;
  const int p = p0 + ty * 4;
  const float* xb = x + (size_t)b * CIN * LEN;
  u16* xTb = xT + (size_t)b * L2V * CIN + (size_t)(PADW + p) * CIN;
#pragma unroll
  for (int half = 0; half < 2; ++half) {
    const int ci0 = half * 64 + tx * 4;
    float r[4][4];
#pragma unroll
    for (int i = 0; i < 4; ++i)
      *(float4*)r[i] = *(const float4*)(xb + (size_t)(ci0 + i) * LEN + p);
#pragma unroll
    for (int j = 0; j < 4; ++j)
      *(ushort4*)(xTb + (size_t)j * CIN + ci0) =
          make_ushort4(f2bf(r[0][j]), f2bf(r[1][j]), f2bf(r[2][j]), f2bf(r[3][j]));
  }
}

// ---------------------------------------------------------------------------
// FUSED conv + g-GEMM (round-12 structure, unchanged).
// ---------------------------------------------------------------------------
__global__ __launch_bounds__(512, 2) void conv_g_fused(
    const u16* __restrict__ wt, const u16* __restrict__ xT,
    const float* __restrict__ c1b, const u16* __restrict__ gwb,
    const float* __restrict__ params, u16* __restrict__ hout,
    u16* __restrict__ gout)
{
  const int b = blockIdx.y;
  const int p0 = blockIdx.x * PTILE;
  const int tid = threadIdx.x;
  const int w = tid >> 6, lane = tid & 63;
  const int l15 = lane & 15, kg = lane >> 4;
  const int wA = w >> 1, wB = w & 1;

  __shared__ u16 hA[PTILE * 256];
  __shared__ u16 pool[40960];

  const u16* xTb = xT + (size_t)b * L2V * CIN + (size_t)p0 * CIN;

  v4f acc[4][4];
#pragma unroll
  for (int i = 0; i < 4; ++i)
#pragma unroll
    for (int j = 0; j < 4; ++j) acc[i][j] = (v4f){0.f, 0.f, 0.f, 0.f};

  auto stageA = [&](int s, int buf) {
    const int t = s >> 2, ci0 = (s & 3) << 5;
    u16* dst = pool + buf * 12288;
#pragma unroll
    for (int i = 0; i < 2; ++i) {
      const int cidx = i * 512 + tid;
      const int row = cidx >> 2, ch = cidx & 3;
      gll16(wt + (size_t)row * KCONV + t * CIN + ci0 + ((ch ^ KEY3(row)) << 3),
            (void*)(dst + cidx * 8));
    }
    {
      const int row = tid >> 2, ch = tid & 3;
      gll16(xTb + (size_t)(2 * t + row) * CIN + ci0 + ((ch ^ KEY3(row)) << 3),
            (void*)(dst + 8192 + tid * 8));
    }
  };

  stageA(0, 0);
  stageA(1, 1);

#pragma unroll
  for (int s = 0; s < 28; ++s) {
    if (s < 27) wait_vm(3); else wait_vm(0);
    BARRIER()
    if (s < 26) stageA(s + 2, (s + 2) % 3);
    const u16* wbuf = pool + (s % 3) * 12288;
    const u16* xbuf = wbuf + 8192;
    v8s a[4], bb[4];
#pragma unroll
    for (int f = 0; f < 4; ++f) {
      const int c = wA * 64 + f * 16 + l15;
      a[f] = *(const v8s*)&wbuf[c * 32 + ((kg ^ KEY3(c)) << 3)];
      const int p = wB * 64 + f * 16 + l15;
      bb[f] = *(const v8s*)&xbuf[p * 32 + ((kg ^ KEY3(p)) << 3)];
    }
    MFMA16(acc, a, bb)
  }

#pragma unroll
  for (int fi = 0; fi < 4; ++fi) {
    const int cb = wA * 64 + fi * 16 + kg * 4;
    const float4 bv = *(const float4*)(c1b + cb);
    const int ch32 = cb >> 3, off = cb & 7;
#pragma unroll
    for (int fj = 0; fj < 4; ++fj) {
      const int p = wB * 64 + fj * 16 + l15;
      *(ushort4*)&hA[p * 256 + ((ch32 ^ (p & 7)) << 3) + off] = make_ushort4(
          f2bf(fmaxf(acc[fi][fj][0] + bv.x, 0.f)),
          f2bf(fmaxf(acc[fi][fj][1] + bv.y, 0.f)),
          f2bf(fmaxf(acc[fi][fj][2] + bv.z, 0.f)),
          f2bf(fmaxf(acc[fi][fj][3] + bv.w, 0.f)));
      acc[fi][fj] = (v4f){0.f, 0.f, 0.f, 0.f};
    }
  }
  LGKM0();
  BARRIER()

  const size_t mg0h = (size_t)b * L2V + PADW + p0;
#pragma unroll
  for (int i = 0; i < 8; ++i) {
    const int chunk = i * 512 + tid;
    const int p = chunk >> 5, ci = chunk & 31;
    const int4 vv = *(const int4*)&hA[p * 256 + ((ci ^ (p & 7)) << 3)];
    *(int4*)(hout + (mg0h + p) * COUT + ci * 8) = vv;
  }

  auto stageB = [&](int s, int buf) {
    u16* dst = pool + buf * 8192;
#pragma unroll
    for (int i = 0; i < 2; ++i) {
      const int cidx = i * 512 + tid;
      const int row = cidx >> 2, ch = cidx & 3;
      gll16(gwb + (size_t)row * COUT + (s << 5) + ((ch ^ KEY3(row)) << 3),
            (void*)(dst + cidx * 8));
    }
  };
  stageB(0, 0);
  stageB(1, 1);

#pragma unroll
  for (int s = 0; s < 8; ++s) {
    if (s < 7) wait_vm(2); else wait_vm(0);
    BARRIER()
    if (s < 6) stageB(s + 2, (s + 2) % 3);
    const u16* nbuf = pool + (s % 3) * 8192;
    v8s a[4], bb[4];
#pragma unroll
    for (int f = 0; f < 4; ++f) {
      const int n = wA * 64 + f * 16 + l15;
      a[f] = *(const v8s*)&nbuf[n * 32 + ((kg ^ KEY3(n)) << 3)];
      const int m = wB * 64 + f * 16 + l15;
      bb[f] = *(const v8s*)&hA[m * 256 + ((((s << 2) + kg) ^ (m & 7)) << 3)];
    }
    MFMA16(acc, a, bb)
  }

  u16* T = pool + 24576;
#pragma unroll
  for (int h2 = 0; h2 < 2; ++h2) {
    if ((wA >> 1) == h2) {
#pragma unroll
      for (int fi = 0; fi < 4; ++fi) {
        const int jj = (wA & 1) * 64 + fi * 16 + kg * 4;
        const float4 bv = *(const float4*)(params + h2 * 128 + jj);
        const int jc = jj >> 3, joff = jj & 7;
#pragma unroll
        for (int fj = 0; fj < 4; ++fj) {
          const int m = wB * 64 + fj * 16 + l15;
          *(ushort4*)&T[m * 128 + ((jc ^ (m & 15)) << 3) + joff] = make_ushort4(
              f2bf(acc[fi][fj][0] + bv.x), f2bf(acc[fi][fj][1] + bv.y),
              f2bf(acc[fi][fj][2] + bv.z), f2bf(acc[fi][fj][3] + bv.w));
        }
      }
    }
    LGKM0();
    BARRIER()
#pragma unroll
    for (int i2 = 0; i2 < 4; ++i2) {
      const int chunk = i2 * 512 + tid;
      const int m = chunk >> 4, j16 = chunk & 15;
      const int4 vv = *(const int4*)&T[m * 128 + ((j16 ^ (m & 15)) << 3)];
      *(int4*)(gout + (mg0h + m) * COUT + h2 * 128 + j16 * 8) = vv;
    }
    LGKM0();
    BARRIER()
  }
}

// ---------------------------------------------------------------------------
// Attention v3: 4 queries per wave, 16 lanes per query (sub = lane>>4,
// cg = lane&15 owns 16 channels).  Per-query reduce = 4 intra-group shuffles.
// score[t] = g_j . h_pos + rpb  (the h_j-dependent term is softmax-invariant)
// out s_j = sum_t softmax_t * h_pos
// ---------------------------------------------------------------------------
__global__ __launch_bounds__(256) void attn_v3(
    const u16* __restrict__ h, const u16* __restrict__ g,
    const float* __restrict__ rpb, u16* __restrict__ sout)
{
  const int wid = blockIdx.x * 4 + (threadIdx.x >> 6);
  const int lane = threadIdx.x & 63;
  const int sub = lane >> 4, cg = lane & 15;
  const int q = wid * 4 + sub;              // global query 0..32767
  const int b = q >> 12;
  const int j = q & 4095;
  const int r = j & 1, ii = j >> 1;
  int start = ii - 3;
  start = start < 0 ? 0 : start;
  start = start > 2047 ? 2047 : start;

  const u16* hb = h + (size_t)b * L2V * COUT;
  const u16* gb = g + (size_t)b * L2V * COUT;
  const int co = cg * 16;

  // g fragment: 16 channels -> 16 floats
  float gf[16];
  {
    const int4 g0 = *(const int4*)(gb + (size_t)j * COUT + co);
    const int4 g1 = *(const int4*)(gb + (size_t)j * COUT + co + 8);
    const int gw[8] = {g0.x, g0.y, g0.z, g0.w, g1.x, g1.y, g1.z, g1.w};
#pragma unroll
    for (int i = 0; i < 8; ++i) {
      const unsigned int u = (unsigned int)gw[i];
      gf[2 * i]     = __uint_as_float(u << 16);
      gf[2 * i + 1] = __uint_as_float(u & 0xffff0000u);
    }
  }

  int4 hp0[7], hp1[7];
  float sc[7];
  float mx = -1e30f;
#pragma unroll
  for (int t = 0; t < 7; ++t) {
    const int pos = r + 2 * (start + t);
    const u16* hrow = hb + (size_t)pos * COUT + co;
    hp0[t] = *(const int4*)(hrow);
    hp1[t] = *(const int4*)(hrow + 8);
    const int hw[8] = {hp0[t].x, hp0[t].y, hp0[t].z, hp0[t].w,
                       hp1[t].x, hp1[t].y, hp1[t].z, hp1[t].w};
    float s = 0.f;
#pragma unroll
    for (int i = 0; i < 8; ++i) {
      const unsigned int u = (unsigned int)hw[i];
      s += gf[2 * i]     * __uint_as_float(u << 16);
      s += gf[2 * i + 1] * __uint_as_float(u & 0xffff0000u);
    }
    s += __shfl_xor(s, 1); s += __shfl_xor(s, 2);
    s += __shfl_xor(s, 4); s += __shfl_xor(s, 8);
    s += rpb[start + t - ii + 6];
    sc[t] = s;
    mx = fmaxf(mx, s);
  }
  float sum = 0.f;
#pragma unroll
  for (int t = 0; t < 7; ++t) { sc[t] = __expf(sc[t] - mx); sum += sc[t]; }
  const float inv = 1.f / sum;

  float acc[16];
#pragma unroll
  for (int i = 0; i < 16; ++i) acc[i] = 0.f;
#pragma unroll
  for (int t = 0; t < 7; ++t) {
    const float wgt = sc[t] * inv;
    const int hw[8] = {hp0[t].x, hp0[t].y, hp0[t].z, hp0[t].w,
                       hp1[t].x, hp1[t].y, hp1[t].z, hp1[t].w};
#pragma unroll
    for (int i = 0; i < 8; ++i) {
      const unsigned int u = (unsigned int)hw[i];
      acc[2 * i]     += wgt * __uint_as_float(u << 16);
      acc[2 * i + 1] += wgt * __uint_as_float(u & 0xffff0000u);
    }
  }
  u16* dst = sout + ((size_t)(b * LEN + j)) * COUT + co;
  ushort4 o0 = make_ushort4(f2bf(acc[0]), f2bf(acc[1]), f2bf(acc[2]), f2bf(acc[3]));
  ushort4 o1 = make_ushort4(f2bf(acc[4]), f2bf(acc[5]), f2bf(acc[6]), f2bf(acc[7]));
  ushort4 o2 = make_ushort4(f2bf(acc[8]), f2bf(acc[9]), f2bf(acc[10]), f2bf(acc[11]));
  ushort4 o3 = make_ushort4(f2bf(acc[12]), f2bf(acc[13]), f2bf(acc[14]), f2bf(acc[15]));
  *(ushort4*)(dst) = o0;  *(ushort4*)(dst + 4) = o1;
  *(ushort4*)(dst + 8) = o2; *(ushort4*)(dst + 12) = o3;
}

// ---------------------------------------------------------------------------
// fused proj(+folded v) + ds residual + double relu. (unchanged from r12)
// ---------------------------------------------------------------------------
__global__ __launch_bounds__(256, 2) void projds_gll(
    const u16* __restrict__ ao, const u16* __restrict__ pwb,
    const float* __restrict__ pb, const u16* __restrict__ xT,
    const u16* __restrict__ dwb, const float* __restrict__ db,
    float* __restrict__ out)
{
  const int b = blockIdx.z;
  const int l0 = blockIdx.x * 128, o0 = blockIdx.y * 128;
  const int tid = threadIdx.x;
  const int w = tid >> 6, lane = tid & 63;
  const int l15 = lane & 15, kg = lane >> 4;
  const int wr = w >> 1, wc = w & 1;

  __shared__ u16 sX[2][128 * 32];
  __shared__ u16 sW[2][128 * 32];

  const int arow = tid >> 2, ach = tid & 3;
  const int akey = KEY3(arow);
  const u16* aob = ao + (size_t)b * LEN * COUT;
  const u16* xTb = xT + ((size_t)b * L2V + PADW) * CIN;

  auto stage1 = [&](int s, int buf) {
#pragma unroll
    for (int i = 0; i < 2; ++i) {
      const int row = i * 64 + arow;
      const int sl = (ach ^ akey) << 3;
      gll16(aob + (size_t)(l0 + row) * COUT + (s << 5) + sl,
            (void*)&sX[buf][(i * 256 + tid) * 8]);
      gll16(pwb + (size_t)(o0 + row) * COUT + (s << 5) + sl,
            (void*)&sW[buf][(i * 256 + tid) * 8]);
    }
  };
  auto stage2 = [&](int s, int buf) {
#pragma unroll
    for (int i = 0; i < 2; ++i) {
      const int row = i * 64 + arow;
      const int sl = (ach ^ akey) << 3;
      gll16(xTb + (size_t)(l0 + row) * CIN + (s << 5) + sl,
            (void*)&sX[buf][(i * 256 + tid) * 8]);
      gll16(dwb + (size_t)(o0 + row) * CIN + (s << 5) + sl,
            (void*)&sW[buf][(i * 256 + tid) * 8]);
    }
  };

  v4f acc[4][4];
#pragma unroll
  for (int i = 0; i < 4; ++i)
#pragma unroll
    for (int j = 0; j < 4; ++j) acc[i][j] = (v4f){0.f, 0.f, 0.f, 0.f};

  stage1(0, 0);
  __syncthreads();
  for (int ss = 0; ss < 12; ++ss) {
    const int buf = ss & 1;
    if (ss < 7) stage1(ss + 1, buf ^ 1);
    else if (ss < 11) stage2(ss - 7, buf ^ 1);
    v8s a[4], bb[4];
#pragma unroll
    for (int f = 0; f < 4; ++f) {
      const int lr = wr * 64 + f * 16 + l15;
      a[f] = *(const v8s*)&sX[buf][lr * 32 + ((kg ^ KEY3(lr)) << 3)];
      const int orr = wc * 64 + f * 16 + l15;
      bb[f] = *(const v8s*)&sW[buf][orr * 32 + ((kg ^ KEY3(orr)) << 3)];
    }
#pragma unroll
    for (int fi_ = 0; fi_ < 4; ++fi_)
#pragma unroll
      for (int fj_ = 0; fj_ < 4; ++fj_)
        acc[fi_][fj_] = __builtin_amdgcn_mfma_f32_16x16x32_bf16(
            a[fi_], bb[fj_], acc[fi_][fj_], 0, 0, 0);
    if (ss == 7) {
#pragma unroll
      for (int fj = 0; fj < 4; ++fj) {
        const float pbv = pb[o0 + wc * 64 + fj * 16 + l15];
#pragma unroll
        for (int fi = 0; fi < 4; ++fi)
#pragma unroll
          for (int jj = 0; jj < 4; ++jj)
            acc[fi][fj][jj] = fmaxf(acc[fi][fj][jj] + pbv, 0.f);
      }
    }
    __syncthreads();
  }

#pragma unroll
  for (int fj = 0; fj < 4; ++fj) {
    const int o = o0 + wc * 64 + fj * 16 + l15;
    const float dbv = db[o];
    float* orow = out + ((size_t)(b * COUT + o)) * LEN;
#pragma unroll
    for (int fi = 0; fi < 4; ++fi) {
      const int lb = l0 + wr * 64 + fi * 16 + kg * 4;
      float v0 = acc[fi][fj][0] + dbv; v0 = v0 > 0.f ? v0 : 0.f;
      float v1 = acc[fi][fj][1] + dbv; v1 = v1 > 0.f ? v1 : 0.f;
      float v2 = acc[fi][fj][2] + dbv; v2 = v2 > 0.f ? v2 : 0.f;
      float v3 = acc[fi][fj][3] + dbv; v3 = v3 > 0.f ? v3 : 0.f;
      *(float4*)(orow + lb) = make_float4(v0, v1, v2, v3);
    }
  }
}

// ---------------------------------------------------------------------------
extern "C" void kernel_launch(void* const* d_in, const int* in_sizes, int n_in,
                              void* d_out, int out_size, void* d_ws, size_t ws_size,
                              hipStream_t stream)
{
  (void)in_sizes; (void)n_in; (void)out_size; (void)ws_size;
  const float* x   = (const float*)d_in[0];
  const float* c1v = (const float*)d_in[1];
  const float* c1g = (const float*)d_in[2];
  const float* c1b = (const float*)d_in[3];
  const float* qw  = (const float*)d_in[4];
  const float* qb  = (const float*)d_in[5];
  const float* rpb = (const float*)d_in[6];
  const float* pw  = (const float*)d_in[7];
  const float* pb  = (const float*)d_in[8];
  const float* dw  = (const float*)d_in[9];
  const float* db  = (const float*)d_in[10];
  float* out = (float*)d_out;

  char* ws = (char*)d_ws;
  u16*   wt     = (u16*)(ws);                    //   458,752 B
  u16*   gwb    = (u16*)(ws + 458752);           //   131,072 B
  u16*   mpv    = (u16*)(ws + 589824);           //   131,072 B
  u16*   dwb    = (u16*)(ws + 720896);           //    65,536 B
  float* params = (float*)(ws + 786432);         //     4,096 B (u,-,bpv)
  u16*   xT     = (u16*)(ws + 1048576);          // 8,413,184 B
  u16*   h      = (u16*)(ws + 9461760);          // 16,826,368 B
  u16*   g      = (u16*)(ws + 26288128);         // 16,826,368 B
  u16*   s      = (u16*)(ws + 43114496);         // 16,777,216 B

  prep_wn<<<COUT, 256, 0, stream>>>(c1v, c1g, wt);
  prep_fold<<<dim3(4, 4, 2), 256, 0, stream>>>(qw, pw, gwb, mpv);
  fold_misc<<<386, 256, 0, stream>>>(qw, qb, pw, pb, dw, params, dwb);
  zero_fill2<<<240, 256, 0, stream>>>(xT, h, g, params);
  xpose<<<dim3(LEN / 64, BATCH), 256, 0, stream>>>(x, xT);
  conv_g_fused<<<dim3(LEN / PTILE, BATCH), 512, 0, stream>>>(wt, xT, c1b, gwb, params, h, g);
  attn_v3<<<(BATCH * LEN) / 16, 256, 0, stream>>>(h, g, rpb, s);
  projds_gll<<<dim3(LEN / 128, COUT / 128, BATCH), 256, 0, stream>>>(
      s, mpv, params + 512, xT, dwb, db, out);
}